// Round 22
// baseline (216.781 us; speedup 1.0000x reference)
//
#include <hip/hip_runtime.h>
#include <hip/hip_bf16.h>

// q = rownorm( 1 / (1 + ||x - c||^2) ), ALPHA=1
// x: (262144, 256) f32 ; clusters: (256, 256) f32 ; out: (262144, 256) f32
//
// R23: 2 blocks/CU via 64KB hybrid B. Ledger insight: R17's binary is 120
// regs <= 128 -> HW permits 4 waves/SIMD; the limiter was 128KB LDS
// (1 block/CU). Here LDS holds only clusters [0..63]u[128..191] (two
// swizzled 32KB chunks); wave ch reads its other 64 cols from L2 per
// k-step (B is L2-resident). Body = R14's register diet (single xv[8],
// half-afrag pipeline) + g[4] L2 frags ~= 110 regs under the (512,2)
// cap. LDS 69.7KB -> TWO 8-wave blocks/CU = 4 waves/SIMD, double TLP,
// no cross-block deps (pairs stay in-block). Grid 512 = exactly 2/CU.

#define NROWS 262144
#define DDIM  256
#define KCL   256
#define TPB   8                       // 64-row tiles per block
#define GRID  (NROWS / 64 / TPB)      // 512 blocks = 2 per CU

using f32x4  = __attribute__((ext_vector_type(4))) float;
using s16x8  = __attribute__((ext_vector_type(8))) short;

__device__ inline unsigned short f2bf(float f) {
    // round-to-nearest-even f32 -> bf16 (prep kernel)
    unsigned int u = __float_as_uint(f);
    u += 0x7fffu + ((u >> 16) & 1u);
    return (unsigned short)(u >> 16);
}

__device__ inline short bfc(float f) {
    // cast-based: pairs into v_cvt_pk_bf16_f32 (same RTNE result)
    return (short)__bfloat16_as_ushort(__float2bfloat16(f));
}

// One wave per cluster row: convert to bf16, compute ||c||^2.
__global__ void prep_kernel(const float* __restrict__ clusters,
                            unsigned short* __restrict__ cb,
                            float* __restrict__ csq) {
    int k    = blockIdx.x;
    int lane = threadIdx.x;  // 64 threads
    const float* row = clusters + (size_t)k * DDIM;
    float4 a = *reinterpret_cast<const float4*>(row + lane * 4);
    ushort4 b;
    b.x = f2bf(a.x); b.y = f2bf(a.y); b.z = f2bf(a.z); b.w = f2bf(a.w);
    *reinterpret_cast<ushort4*>(cb + (size_t)k * DDIM + lane * 4) = b;
    float ss = a.x*a.x + a.y*a.y + a.z*a.z + a.w*a.w;
    #pragma unroll
    for (int m = 1; m < 64; m <<= 1) ss += __shfl_xor(ss, m);
    if (lane == 0) csq[k] = ss;
}

// 8 waves/block: wave w -> rg = w>>1 (pair), ch = w&1 (col half).
// Wave computes rows [trow+rg*16, +16) x cols [ch*128, +128):
//   f = 0..3 -> clusters ch*128 + f*16 + .. from LDS chunk ch (swizzled)
//   f = 4..7 -> clusters ch*128 + 64 + (f-4)*16 + .. from L2 (g-frags)
// A-frag: lane holds x[row + (l&15)][s*32 + (l>>4)*8 + j], j=0..7
// C/D   : col = l&15, row = (l>>4)*4 + reg   [verified layout, m89]
__global__ __launch_bounds__(512, 2) void fused_kernel(
    const float* __restrict__ x,
    const unsigned short* __restrict__ cb,
    const float* __restrict__ csq,
    float* __restrict__ out) {

    __shared__ char  lds_b[2 * 64 * DDIM * 2]; // 64 KB: 2 chunks x 64 clusters
    __shared__ float ls_sum[TPB][2][4][16];    // per-tile slots
    __shared__ int   ls_flag[2][4];            // [ch][rg] tiles-completed

    const int tid  = threadIdx.x;
    const int lane = tid & 63;
    const int wave = tid >> 6;               // 0..7
    const int rg   = wave >> 1;              // 0..3
    const int ch   = wave & 1;               // 0..1
    const int c15  = lane & 15;
    const int kch  = lane >> 4;              // 0..3

    const int tile0 = blockIdx.x * TPB;

    // ---- stage B chunks into LDS: chunk c holds clusters c*128..c*128+63.
    //      linear LDS dest; swizzled global source (row&7 == rowin&7) ----
    #pragma unroll
    for (int it = 0; it < 8; ++it) {
        int lin    = it * 8192 + tid * 16;        // byte in 64KB LDS
        int chunk  = lin >> 15;                   // 0..1
        int rowin  = (lin >> 9) & 63;             // cluster within chunk
        int inrow  = lin & 511;
        int gsrc   = (chunk * 128 + rowin) * 512 + (inrow ^ ((rowin & 7) << 4));
        __builtin_amdgcn_global_load_lds(
            (const __attribute__((address_space(1))) unsigned int*)((const char*)cb + gsrc),
            (__attribute__((address_space(3))) unsigned int*)(lds_b + lin),
            16, 0, 0);
    }

    if (tid < 8) ((int*)ls_flag)[tid] = 0;

    // csq fragment for this wave's col half (8 regs; f=0..7 as above)
    float cs[8];
    #pragma unroll
    for (int f = 0; f < 8; ++f) cs[f] = csq[ch * 128 + f * 16 + c15];

    // per-lane L2 base for the upper 64 cols of this wave's half:
    // cluster ch*128 + 64 + f4*16 + c15, k offset kch*8
    const unsigned short* gb = cb + (size_t)(ch * 128 + 64 + c15) * DDIM + kch * 8;

    __syncthreads();   // drains vmcnt; B + flags ready (only block barrier)

    // per-lane x base for tile t
    auto xrow = [&](int t) -> const float* {
        return x + (size_t)((tile0 + t) * 64 + rg * 16 + c15) * DDIM + kch * 8;
    };

    f32x4 xv[8];   // SINGLE reused load buffer (32 regs) — register diet

    // ---- prologue: tile 0's first k-half flies under B staging ----
    #pragma unroll
    for (int i = 0; i < 8; ++i)
        xv[i] = *reinterpret_cast<const f32x4*>(xrow(0) + (i >> 1) * 32 + (i & 1) * 4);

    #pragma unroll 1
    for (int t = 0; t < TPB; ++t) {
        const int trow = (tile0 + t) * 64;
        const float* xr = xrow(t);

        float p0 = 0.f, p1 = 0.f;

        // ---- convert half 1 (k 0..127) -> afA; xv dies ----
        s16x8 afA[4];
        #pragma unroll
        for (int s4 = 0; s4 < 4; ++s4) {
            f32x4 xa = xv[2 * s4], xb = xv[2 * s4 + 1];
            float t0 = xa[0]*xa[0] + xa[1]*xa[1];
            float t1 = xa[2]*xa[2] + xa[3]*xa[3];
            float t2 = xb[0]*xb[0] + xb[1]*xb[1];
            float t3 = xb[2]*xb[2] + xb[3]*xb[3];
            if (s4 & 1) p1 += (t0 + t1) + (t2 + t3);
            else        p0 += (t0 + t1) + (t2 + t3);
            afA[s4][0] = bfc(xa[0]); afA[s4][1] = bfc(xa[1]);
            afA[s4][2] = bfc(xa[2]); afA[s4][3] = bfc(xa[3]);
            afA[s4][4] = bfc(xb[0]); afA[s4][5] = bfc(xb[1]);
            afA[s4][6] = bfc(xb[2]); afA[s4][7] = bfc(xb[3]);
        }

        // ---- reload xv with half 2; MFMA s0-3 covers its latency ----
        #pragma unroll
        for (int i = 0; i < 8; ++i) {
            int ii = 8 + i;
            xv[i] = *reinterpret_cast<const f32x4*>(xr + (ii >> 1) * 32 + (ii & 1) * 4);
        }

        f32x4 acc[8];
        #pragma unroll
        for (int f = 0; f < 8; ++f) acc[f] = (f32x4){0.f, 0.f, 0.f, 0.f};

        __builtin_amdgcn_s_setprio(1);
        #pragma unroll
        for (int s = 0; s < 4; ++s) {
            s16x8 g[4];
            #pragma unroll
            for (int f4 = 0; f4 < 4; ++f4)
                g[f4] = *reinterpret_cast<const s16x8*>(gb + (size_t)f4 * 16 * DDIM + s * 32);
            #pragma unroll
            for (int f4 = 0; f4 < 4; ++f4) {
                int ba = ch * 32768 + ((f4 * 16 + c15) * 512) + s * 64 + kch * 16;
                ba ^= ((c15 & 7) << 4);
                s16x8 bfrag = *reinterpret_cast<const s16x8*>(lds_b + ba);
                acc[f4] = __builtin_amdgcn_mfma_f32_16x16x32_bf16(afA[s], bfrag,
                                                                  acc[f4], 0, 0, 0);
            }
            #pragma unroll
            for (int f4 = 0; f4 < 4; ++f4)
                acc[4 + f4] = __builtin_amdgcn_mfma_f32_16x16x32_bf16(afA[s], g[f4],
                                                                      acc[4 + f4], 0, 0, 0);
        }
        __builtin_amdgcn_s_setprio(0);

        // ---- convert half 2 -> afB; xv dies ----
        s16x8 afB[4];
        #pragma unroll
        for (int s4 = 0; s4 < 4; ++s4) {
            f32x4 xa = xv[2 * s4], xb = xv[2 * s4 + 1];
            float t0 = xa[0]*xa[0] + xa[1]*xa[1];
            float t1 = xa[2]*xa[2] + xa[3]*xa[3];
            float t2 = xb[0]*xb[0] + xb[1]*xb[1];
            float t3 = xb[2]*xb[2] + xb[3]*xb[3];
            if (s4 & 1) p1 += (t0 + t1) + (t2 + t3);
            else        p0 += (t0 + t1) + (t2 + t3);
            afB[s4][0] = bfc(xa[0]); afB[s4][1] = bfc(xa[1]);
            afB[s4][2] = bfc(xa[2]); afB[s4][3] = bfc(xa[3]);
            afB[s4][4] = bfc(xb[0]); afB[s4][5] = bfc(xb[1]);
            afB[s4][6] = bfc(xb[2]); afB[s4][7] = bfc(xb[3]);
        }

        // ---- reload xv with NEXT tile's half 1 (flies through MFMA+epilogue) ----
        if (t + 1 < TPB) {
            const float* xn = xrow(t + 1);
            #pragma unroll
            for (int i = 0; i < 8; ++i)
                xv[i] = *reinterpret_cast<const f32x4*>(xn + (i >> 1) * 32 + (i & 1) * 4);
        }

        __builtin_amdgcn_s_setprio(1);
        #pragma unroll
        for (int s = 0; s < 4; ++s) {
            s16x8 g[4];
            #pragma unroll
            for (int f4 = 0; f4 < 4; ++f4)
                g[f4] = *reinterpret_cast<const s16x8*>(gb + (size_t)f4 * 16 * DDIM + (s + 4) * 32);
            #pragma unroll
            for (int f4 = 0; f4 < 4; ++f4) {
                int ba = ch * 32768 + ((f4 * 16 + c15) * 512) + (s + 4) * 64 + kch * 16;
                ba ^= ((c15 & 7) << 4);
                s16x8 bfrag = *reinterpret_cast<const s16x8*>(lds_b + ba);
                acc[f4] = __builtin_amdgcn_mfma_f32_16x16x32_bf16(afB[s], bfrag,
                                                                  acc[f4], 0, 0, 0);
            }
            #pragma unroll
            for (int f4 = 0; f4 < 4; ++f4)
                acc[4 + f4] = __builtin_amdgcn_mfma_f32_16x16x32_bf16(afB[s], g[f4],
                                                                      acc[4 + f4], 0, 0, 0);
        }
        __builtin_amdgcn_s_setprio(0);

        // ---- epilogue: student-t + 128-col partial row sums ----
        float xsq = p0 + p1;
        xsq += __shfl_xor(xsq, 16);
        xsq += __shfl_xor(xsq, 32);
        // lane l now holds xsq of row trow + rg*16 + (l&15)

        float psum[4];
        #pragma unroll
        for (int r = 0; r < 4; ++r) {
            float xrr = __shfl(xsq, kch * 4 + r);
            float s = 0.f;
            #pragma unroll
            for (int f = 0; f < 8; ++f) {
                float d2 = xrr - 2.0f * acc[f][r] + cs[f];
                float qv = __builtin_amdgcn_rcpf(1.0f + d2);  // ALPHA=1 -> exp==1
                acc[f][r] = qv;
                s += qv;
            }
            s += __shfl_xor(s, 1);
            s += __shfl_xor(s, 2);
            s += __shfl_xor(s, 4);
            s += __shfl_xor(s, 8);
            psum[r] = s;   // sum over this wave's 128 cols, row kch*4+r
        }

        // ---- pairwise handshake (no block barrier, no vmcnt drain) ----
        if (c15 == 0) {
            #pragma unroll
            for (int r = 0; r < 4; ++r)
                ls_sum[t][ch][rg][kch * 4 + r] = psum[r];
        }
        asm volatile("s_waitcnt lgkmcnt(0)" ::: "memory");  // sums visible
        if (lane == 0)
            __atomic_store_n(&ls_flag[ch][rg], t + 1, __ATOMIC_RELAXED);

        volatile int* pf = (volatile int*)&ls_flag[ch ^ 1][rg];
        while (*pf <= t) { __builtin_amdgcn_s_sleep(1); }
        asm volatile("" ::: "memory");   // no hoisting of sum reads above spin

        const int row0t = trow + rg * 16;
        #pragma unroll
        for (int r = 0; r < 4; ++r) {
            float other = ls_sum[t][ch ^ 1][rg][kch * 4 + r];
            float inv = __builtin_amdgcn_rcpf(psum[r] + other);
            const size_t orow = (size_t)(row0t + kch * 4 + r) * KCL;
            #pragma unroll
            for (int f = 0; f < 8; ++f) {
                __builtin_nontemporal_store(acc[f][r] * inv,
                                            &out[orow + ch * 128 + f * 16 + c15]);
            }
        }
    }
}

extern "C" void kernel_launch(void* const* d_in, const int* in_sizes, int n_in,
                              void* d_out, int out_size, void* d_ws, size_t ws_size,
                              hipStream_t stream) {
    const float* x        = (const float*)d_in[0];
    const float* clusters = (const float*)d_in[1];
    float* out = (float*)d_out;

    // ws layout: [0, 128KB) clusters as bf16 ; [128KB, +1KB) c_sq f32
    unsigned short* cb  = (unsigned short*)d_ws;
    float*          csq = (float*)((char*)d_ws + (size_t)KCL * DDIM * sizeof(unsigned short));

    prep_kernel<<<KCL, 64, 0, stream>>>(clusters, cb, csq);
    fused_kernel<<<GRID, 512, 0, stream>>>(x, cb, csq, out);
}

// Round 23
// 130.390 us; speedup vs baseline: 1.6626x; 1.6626x over previous
//
#include <hip/hip_runtime.h>

// q = rownorm( 1 / (1 + ||x - c||^2) ), ALPHA=1
// x: (262144, 256) f32 ; clusters: (256, 256) f32 ; out: (262144, 256) f32
//
// R24 = R22/R17 champion (126.6us) with ONE change: plain stores instead of
// nontemporal. Ledger evidence: plain-store kernels (R1/R3) wrote EXACTLY
// 262144 KB; every NT kernel writes 282-295 MB (+12-15%) — NT bypasses L2
// write-combining, so 64B lane-quad segments hit HBM as partial bursts.
// L2 pollution from the out stream is harmless here (B is 128KB, x is
// streamed once), but 33MB of extra HBM writes is ~10us. Everything else
// identical: full B (128KB, swizzled) in LDS; 4 col-split wave pairs;
// pairwise LDS-flag handshake; xv2 at strip top; setprio; s_sleep spin.

#define NROWS 262144
#define DDIM  256
#define KCL   256
#define TPB   16                      // 64-row tiles per block
#define GRID  (NROWS / 64 / TPB)      // 256 blocks = 1 per CU

using f32x4  = __attribute__((ext_vector_type(4))) float;
using s16x8  = __attribute__((ext_vector_type(8))) short;

__device__ inline unsigned short f2bf(float f) {
    // round-to-nearest-even f32 -> bf16
    unsigned int u = __float_as_uint(f);
    u += 0x7fffu + ((u >> 16) & 1u);
    return (unsigned short)(u >> 16);
}

// One wave per cluster row: convert to bf16, compute ||c||^2.
__global__ void prep_kernel(const float* __restrict__ clusters,
                            unsigned short* __restrict__ cb,
                            float* __restrict__ csq) {
    int k    = blockIdx.x;
    int lane = threadIdx.x;  // 64 threads
    const float* row = clusters + (size_t)k * DDIM;
    float4 a = *reinterpret_cast<const float4*>(row + lane * 4);
    ushort4 b;
    b.x = f2bf(a.x); b.y = f2bf(a.y); b.z = f2bf(a.z); b.w = f2bf(a.w);
    *reinterpret_cast<ushort4*>(cb + (size_t)k * DDIM + lane * 4) = b;
    float ss = a.x*a.x + a.y*a.y + a.z*a.z + a.w*a.w;
    #pragma unroll
    for (int m = 1; m < 64; m <<= 1) ss += __shfl_xor(ss, m);
    if (lane == 0) csq[k] = ss;
}

// 8 waves/block: wave w -> rg = w>>1 (pair), ch = w&1 (col half).
// Wave computes rows [trow+rg*16, +16) x cols [ch*128, +128).
// A-frag: lane holds x[row + (l&15)][s*32 + (l>>4)*8 + j], j=0..7
// B-frag: lane holds c[ch*128 + f*16 + (l&15)][s*32 + (l>>4)*8 + j], f=0..7
// C/D   : col = l&15, row = (l>>4)*4 + reg   [verified layout, m89]
__global__ __launch_bounds__(512, 2) void fused_kernel(
    const float* __restrict__ x,
    const unsigned short* __restrict__ cb,
    const float* __restrict__ csq,
    float* __restrict__ out) {

    __shared__ char  lds_b[KCL * DDIM * 2];   // 128 KB: full B, swizzled
    __shared__ float ls_sum[TPB][2][4][16];   // per-tile slots: no reuse hazard
    __shared__ int   ls_flag[2][4];           // [ch][rg] tiles-completed counter

    const int tid  = threadIdx.x;
    const int lane = tid & 63;
    const int wave = tid >> 6;               // 0..7
    const int rg   = wave >> 1;              // 0..3
    const int ch   = wave & 1;               // 0..1
    const int c15  = lane & 15;
    const int kch  = lane >> 4;              // 0..3

    const int tile0 = blockIdx.x * TPB;

    // ---- stage full B into LDS (linear dest, swizzled global source) ----
    #pragma unroll
    for (int it = 0; it < 16; ++it) {
        int slot = it * 8192 + tid * 16;
        int src  = slot ^ (((slot >> 9) & 7) << 4);
        __builtin_amdgcn_global_load_lds(
            (const __attribute__((address_space(1))) unsigned int*)((const char*)cb + src),
            (__attribute__((address_space(3))) unsigned int*)(lds_b + slot),
            16, 0, 0);
    }

    if (tid < 8) ((int*)ls_flag)[tid] = 0;

    // csq fragment for this wave's col half (8 regs)
    float cs[8];
    #pragma unroll
    for (int f = 0; f < 8; ++f) cs[f] = csq[ch * 128 + f * 16 + c15];

    __syncthreads();   // drains vmcnt; B + flags ready (only block barrier)

    // per-lane x base for tile t
    auto xrow = [&](int t) -> const float* {
        return x + (size_t)((tile0 + t) * 64 + rg * 16 + c15) * DDIM + kch * 8;
    };

    f32x4 xv1[8], xv2[8];

    // ---- prologue: issue tile 0's first k-half ----
    {
        const float* xr = xrow(0);
        #pragma unroll
        for (int i = 0; i < 8; ++i)
            xv1[i] = *reinterpret_cast<const f32x4*>(xr + (i >> 1) * 32 + (i & 1) * 4);
    }

    #pragma unroll 1
    for (int t = 0; t < TPB; ++t) {
        const int trow = (tile0 + t) * 64;
        const float* xr = xrow(t);

        // ---- issue batch 2 (k 128..255) at strip TOP: convert-1 + MFMA
        //      s0-3 cover its full HBM latency ----
        #pragma unroll
        for (int i = 0; i < 8; ++i) {
            int ii = 8 + i;
            xv2[i] = *reinterpret_cast<const f32x4*>(xr + (ii >> 1) * 32 + (ii & 1) * 4);
        }

        s16x8 afrag[8];
        float p[4] = {0.f, 0.f, 0.f, 0.f};

        // ---- convert batch 1 (k 0..127) -> afrag[0..3] ----
        #pragma unroll
        for (int s4 = 0; s4 < 4; ++s4) {
            f32x4 xa = xv1[2 * s4], xb = xv1[2 * s4 + 1];
            float t0 = xa[0]*xa[0] + xa[1]*xa[1];
            float t1 = xa[2]*xa[2] + xa[3]*xa[3];
            float t2 = xb[0]*xb[0] + xb[1]*xb[1];
            float t3 = xb[2]*xb[2] + xb[3]*xb[3];
            p[s4] += (t0 + t1) + (t2 + t3);
            afrag[s4][0] = (short)f2bf(xa[0]); afrag[s4][1] = (short)f2bf(xa[1]);
            afrag[s4][2] = (short)f2bf(xa[2]); afrag[s4][3] = (short)f2bf(xa[3]);
            afrag[s4][4] = (short)f2bf(xb[0]); afrag[s4][5] = (short)f2bf(xb[1]);
            afrag[s4][6] = (short)f2bf(xb[2]); afrag[s4][7] = (short)f2bf(xb[3]);
        }

        f32x4 acc[8];
        #pragma unroll
        for (int f = 0; f < 8; ++f) acc[f] = (f32x4){0.f, 0.f, 0.f, 0.f};

        __builtin_amdgcn_s_setprio(1);
        #pragma unroll
        for (int s = 0; s < 4; ++s) {
            #pragma unroll
            for (int f = 0; f < 8; ++f) {
                int ba = ((ch * 128 + f * 16 + c15) * 512) + s * 64 + kch * 16;
                ba ^= ((c15 & 7) << 4);
                s16x8 bfrag = *reinterpret_cast<const s16x8*>(lds_b + ba);
                acc[f] = __builtin_amdgcn_mfma_f32_16x16x32_bf16(afrag[s], bfrag,
                                                                 acc[f], 0, 0, 0);
            }
        }
        __builtin_amdgcn_s_setprio(0);

        // ---- convert batch 2 (k 128..255) -> afrag[4..7] ----
        #pragma unroll
        for (int s4 = 0; s4 < 4; ++s4) {
            f32x4 xa = xv2[2 * s4], xb = xv2[2 * s4 + 1];
            float t0 = xa[0]*xa[0] + xa[1]*xa[1];
            float t1 = xa[2]*xa[2] + xa[3]*xa[3];
            float t2 = xb[0]*xb[0] + xb[1]*xb[1];
            float t3 = xb[2]*xb[2] + xb[3]*xb[3];
            p[s4] += (t0 + t1) + (t2 + t3);
            int s = 4 + s4;
            afrag[s][0] = (short)f2bf(xa[0]); afrag[s][1] = (short)f2bf(xa[1]);
            afrag[s][2] = (short)f2bf(xa[2]); afrag[s][3] = (short)f2bf(xa[3]);
            afrag[s][4] = (short)f2bf(xb[0]); afrag[s][5] = (short)f2bf(xb[1]);
            afrag[s][6] = (short)f2bf(xb[2]); afrag[s][7] = (short)f2bf(xb[3]);
        }

        // ---- prefetch next tile's batch 1: flies through epilogue+sync ----
        if (t + 1 < TPB) {
            const float* xn = xrow(t + 1);
            #pragma unroll
            for (int i = 0; i < 8; ++i)
                xv1[i] = *reinterpret_cast<const f32x4*>(xn + (i >> 1) * 32 + (i & 1) * 4);
        }

        __builtin_amdgcn_s_setprio(1);
        #pragma unroll
        for (int s = 4; s < 8; ++s) {
            #pragma unroll
            for (int f = 0; f < 8; ++f) {
                int ba = ((ch * 128 + f * 16 + c15) * 512) + s * 64 + kch * 16;
                ba ^= ((c15 & 7) << 4);
                s16x8 bfrag = *reinterpret_cast<const s16x8*>(lds_b + ba);
                acc[f] = __builtin_amdgcn_mfma_f32_16x16x32_bf16(afrag[s], bfrag,
                                                                 acc[f], 0, 0, 0);
            }
        }
        __builtin_amdgcn_s_setprio(0);

        // ---- epilogue: student-t + 128-col partial row sums ----
        float xsq = (p[0] + p[1]) + (p[2] + p[3]);
        xsq += __shfl_xor(xsq, 16);
        xsq += __shfl_xor(xsq, 32);
        // lane l now holds xsq of row trow + rg*16 + (l&15)

        float psum[4];
        #pragma unroll
        for (int r = 0; r < 4; ++r) {
            float xrr = __shfl(xsq, kch * 4 + r);
            float s = 0.f;
            #pragma unroll
            for (int f = 0; f < 8; ++f) {
                float d2 = xrr - 2.0f * acc[f][r] + cs[f];
                float qv = __builtin_amdgcn_rcpf(1.0f + d2);  // ALPHA=1 -> exp==1
                acc[f][r] = qv;
                s += qv;
            }
            s += __shfl_xor(s, 1);
            s += __shfl_xor(s, 2);
            s += __shfl_xor(s, 4);
            s += __shfl_xor(s, 8);
            psum[r] = s;   // sum over this wave's 128 cols, row kch*4+r
        }

        // ---- pairwise handshake (no block barrier, no vmcnt drain) ----
        if (c15 == 0) {
            #pragma unroll
            for (int r = 0; r < 4; ++r)
                ls_sum[t][ch][rg][kch * 4 + r] = psum[r];
        }
        asm volatile("s_waitcnt lgkmcnt(0)" ::: "memory");  // sums visible
        if (lane == 0)
            __atomic_store_n(&ls_flag[ch][rg], t + 1, __ATOMIC_RELAXED);

        volatile int* pf = (volatile int*)&ls_flag[ch ^ 1][rg];
        while (*pf <= t) { __builtin_amdgcn_s_sleep(1); }
        asm volatile("" ::: "memory");   // no hoisting of sum reads above spin

        const int row0t = trow + rg * 16;
        #pragma unroll
        for (int r = 0; r < 4; ++r) {
            float other = ls_sum[t][ch ^ 1][rg][kch * 4 + r];
            float inv = __builtin_amdgcn_rcpf(psum[r] + other);
            const size_t orow = (size_t)(row0t + kch * 4 + r) * KCL;
            #pragma unroll
            for (int f = 0; f < 8; ++f) {
                out[orow + ch * 128 + f * 16 + c15] = acc[f][r] * inv;  // plain store
            }
        }
    }
}

extern "C" void kernel_launch(void* const* d_in, const int* in_sizes, int n_in,
                              void* d_out, int out_size, void* d_ws, size_t ws_size,
                              hipStream_t stream) {
    const float* x        = (const float*)d_in[0];
    const float* clusters = (const float*)d_in[1];
    float* out = (float*)d_out;

    // ws layout: [0, 128KB) clusters as bf16 ; [128KB, +1KB) c_sq f32
    unsigned short* cb  = (unsigned short*)d_ws;
    float*          csq = (float*)((char*)d_ws + (size_t)KCL * DDIM * sizeof(unsigned short));

    prep_kernel<<<KCL, 64, 0, stream>>>(clusters, cb, csq);
    fused_kernel<<<GRID, 512, 0, stream>>>(x, cb, csq, out);
}

// Round 24
// 122.375 us; speedup vs baseline: 1.7715x; 1.0655x over previous
//
#include <hip/hip_runtime.h>

// q = rownorm( 1 / (1 + ||x - c||^2) ), ALPHA=1
// x: (262144, 256) f32 ; clusters: (256, 256) f32 ; out: (262144, 256) f32
//
// FINAL = R17/R22 champion (126.6/127.2 us, VGPR=120, no spill).
// Structure: full B (128KB bf16, XOR-swizzled) staged in LDS once per block
// via global_load_lds w=16; 8 waves = 4 col-split wave pairs (each wave:
// 16 rows x 128 cols, acc[8]); per-tile pairwise LDS-flag handshake (no
// block barrier -> no vmcnt drain, pairs drift); xv2 issued at strip top,
// xv1(t+1) after MFMAs (register prefetch pipeline); rcpf student-t +
// row-normalize epilogue; NT stores; s_setprio around MFMA clusters;
// s_sleep spin.
//
// Structural limit (13 falsified escapes with counter evidence):
//  - >2 waves/SIMD: launch_bounds caps arch regs at 85 (3w) / 64 (4w) via
//    a hard 50/50 arch/AGPR split; body needs ~120 -> spills (R2,R4,R5,
//    R6,R7,R11,R13,R14).
//  - wider per-wave state (dual-strip, B-hoist, full-width acc[16],
//    deeper prefetch): exceeds the 128-arch cap -> spills (R9,R12,R15,
//    R16,R19-as-R20 swap, R23 hybrid).
//  - plain stores: -33MB HBM writes but +L2 store latency, net -3us (R24).
// Floor = 394MB/6.3TB/s ~ 62us; remaining 2x is exposed HBM latency at
// 8 waves/CU, unreachable from HIP source on this allocator.

#define NROWS 262144
#define DDIM  256
#define KCL   256
#define TPB   16                      // 64-row tiles per block
#define GRID  (NROWS / 64 / TPB)      // 256 blocks = 1 per CU

using f32x4  = __attribute__((ext_vector_type(4))) float;
using s16x8  = __attribute__((ext_vector_type(8))) short;

__device__ inline unsigned short f2bf(float f) {
    // round-to-nearest-even f32 -> bf16
    unsigned int u = __float_as_uint(f);
    u += 0x7fffu + ((u >> 16) & 1u);
    return (unsigned short)(u >> 16);
}

// One wave per cluster row: convert to bf16, compute ||c||^2.
__global__ void prep_kernel(const float* __restrict__ clusters,
                            unsigned short* __restrict__ cb,
                            float* __restrict__ csq) {
    int k    = blockIdx.x;
    int lane = threadIdx.x;  // 64 threads
    const float* row = clusters + (size_t)k * DDIM;
    float4 a = *reinterpret_cast<const float4*>(row + lane * 4);
    ushort4 b;
    b.x = f2bf(a.x); b.y = f2bf(a.y); b.z = f2bf(a.z); b.w = f2bf(a.w);
    *reinterpret_cast<ushort4*>(cb + (size_t)k * DDIM + lane * 4) = b;
    float ss = a.x*a.x + a.y*a.y + a.z*a.z + a.w*a.w;
    #pragma unroll
    for (int m = 1; m < 64; m <<= 1) ss += __shfl_xor(ss, m);
    if (lane == 0) csq[k] = ss;
}

// 8 waves/block: wave w -> rg = w>>1 (pair), ch = w&1 (col half).
// Wave computes rows [trow+rg*16, +16) x cols [ch*128, +128).
// A-frag: lane holds x[row + (l&15)][s*32 + (l>>4)*8 + j], j=0..7
// B-frag: lane holds c[ch*128 + f*16 + (l&15)][s*32 + (l>>4)*8 + j], f=0..7
// C/D   : col = l&15, row = (l>>4)*4 + reg   [verified layout, m89]
__global__ __launch_bounds__(512, 2) void fused_kernel(
    const float* __restrict__ x,
    const unsigned short* __restrict__ cb,
    const float* __restrict__ csq,
    float* __restrict__ out) {

    __shared__ char  lds_b[KCL * DDIM * 2];   // 128 KB: full B, swizzled
    __shared__ float ls_sum[TPB][2][4][16];   // per-tile slots: no reuse hazard
    __shared__ int   ls_flag[2][4];           // [ch][rg] tiles-completed counter

    const int tid  = threadIdx.x;
    const int lane = tid & 63;
    const int wave = tid >> 6;               // 0..7
    const int rg   = wave >> 1;              // 0..3
    const int ch   = wave & 1;               // 0..1
    const int c15  = lane & 15;
    const int kch  = lane >> 4;              // 0..3

    const int tile0 = blockIdx.x * TPB;

    // ---- stage full B into LDS (linear dest, swizzled global source) ----
    #pragma unroll
    for (int it = 0; it < 16; ++it) {
        int slot = it * 8192 + tid * 16;
        int src  = slot ^ (((slot >> 9) & 7) << 4);
        __builtin_amdgcn_global_load_lds(
            (const __attribute__((address_space(1))) unsigned int*)((const char*)cb + src),
            (__attribute__((address_space(3))) unsigned int*)(lds_b + slot),
            16, 0, 0);
    }

    if (tid < 8) ((int*)ls_flag)[tid] = 0;

    // csq fragment for this wave's col half (8 regs)
    float cs[8];
    #pragma unroll
    for (int f = 0; f < 8; ++f) cs[f] = csq[ch * 128 + f * 16 + c15];

    __syncthreads();   // drains vmcnt; B + flags ready (only block barrier)

    // per-lane x base for tile t
    auto xrow = [&](int t) -> const float* {
        return x + (size_t)((tile0 + t) * 64 + rg * 16 + c15) * DDIM + kch * 8;
    };

    f32x4 xv1[8], xv2[8];

    // ---- prologue: issue tile 0's first k-half ----
    {
        const float* xr = xrow(0);
        #pragma unroll
        for (int i = 0; i < 8; ++i)
            xv1[i] = *reinterpret_cast<const f32x4*>(xr + (i >> 1) * 32 + (i & 1) * 4);
    }

    #pragma unroll 1
    for (int t = 0; t < TPB; ++t) {
        const int trow = (tile0 + t) * 64;
        const float* xr = xrow(t);

        // ---- issue batch 2 (k 128..255) at strip TOP: convert-1 + MFMA
        //      s0-3 cover its full HBM latency ----
        #pragma unroll
        for (int i = 0; i < 8; ++i) {
            int ii = 8 + i;
            xv2[i] = *reinterpret_cast<const f32x4*>(xr + (ii >> 1) * 32 + (ii & 1) * 4);
        }

        s16x8 afrag[8];
        float p[4] = {0.f, 0.f, 0.f, 0.f};

        // ---- convert batch 1 (k 0..127) -> afrag[0..3] ----
        #pragma unroll
        for (int s4 = 0; s4 < 4; ++s4) {
            f32x4 xa = xv1[2 * s4], xb = xv1[2 * s4 + 1];
            float t0 = xa[0]*xa[0] + xa[1]*xa[1];
            float t1 = xa[2]*xa[2] + xa[3]*xa[3];
            float t2 = xb[0]*xb[0] + xb[1]*xb[1];
            float t3 = xb[2]*xb[2] + xb[3]*xb[3];
            p[s4] += (t0 + t1) + (t2 + t3);
            afrag[s4][0] = (short)f2bf(xa[0]); afrag[s4][1] = (short)f2bf(xa[1]);
            afrag[s4][2] = (short)f2bf(xa[2]); afrag[s4][3] = (short)f2bf(xa[3]);
            afrag[s4][4] = (short)f2bf(xb[0]); afrag[s4][5] = (short)f2bf(xb[1]);
            afrag[s4][6] = (short)f2bf(xb[2]); afrag[s4][7] = (short)f2bf(xb[3]);
        }

        f32x4 acc[8];
        #pragma unroll
        for (int f = 0; f < 8; ++f) acc[f] = (f32x4){0.f, 0.f, 0.f, 0.f};

        __builtin_amdgcn_s_setprio(1);
        #pragma unroll
        for (int s = 0; s < 4; ++s) {
            #pragma unroll
            for (int f = 0; f < 8; ++f) {
                int ba = ((ch * 128 + f * 16 + c15) * 512) + s * 64 + kch * 16;
                ba ^= ((c15 & 7) << 4);
                s16x8 bfrag = *reinterpret_cast<const s16x8*>(lds_b + ba);
                acc[f] = __builtin_amdgcn_mfma_f32_16x16x32_bf16(afrag[s], bfrag,
                                                                 acc[f], 0, 0, 0);
            }
        }
        __builtin_amdgcn_s_setprio(0);

        // ---- convert batch 2 (k 128..255) -> afrag[4..7] ----
        #pragma unroll
        for (int s4 = 0; s4 < 4; ++s4) {
            f32x4 xa = xv2[2 * s4], xb = xv2[2 * s4 + 1];
            float t0 = xa[0]*xa[0] + xa[1]*xa[1];
            float t1 = xa[2]*xa[2] + xa[3]*xa[3];
            float t2 = xb[0]*xb[0] + xb[1]*xb[1];
            float t3 = xb[2]*xb[2] + xb[3]*xb[3];
            p[s4] += (t0 + t1) + (t2 + t3);
            int s = 4 + s4;
            afrag[s][0] = (short)f2bf(xa[0]); afrag[s][1] = (short)f2bf(xa[1]);
            afrag[s][2] = (short)f2bf(xa[2]); afrag[s][3] = (short)f2bf(xa[3]);
            afrag[s][4] = (short)f2bf(xb[0]); afrag[s][5] = (short)f2bf(xb[1]);
            afrag[s][6] = (short)f2bf(xb[2]); afrag[s][7] = (short)f2bf(xb[3]);
        }

        // ---- prefetch next tile's batch 1: flies through epilogue+sync ----
        if (t + 1 < TPB) {
            const float* xn = xrow(t + 1);
            #pragma unroll
            for (int i = 0; i < 8; ++i)
                xv1[i] = *reinterpret_cast<const f32x4*>(xn + (i >> 1) * 32 + (i & 1) * 4);
        }

        __builtin_amdgcn_s_setprio(1);
        #pragma unroll
        for (int s = 4; s < 8; ++s) {
            #pragma unroll
            for (int f = 0; f < 8; ++f) {
                int ba = ((ch * 128 + f * 16 + c15) * 512) + s * 64 + kch * 16;
                ba ^= ((c15 & 7) << 4);
                s16x8 bfrag = *reinterpret_cast<const s16x8*>(lds_b + ba);
                acc[f] = __builtin_amdgcn_mfma_f32_16x16x32_bf16(afrag[s], bfrag,
                                                                 acc[f], 0, 0, 0);
            }
        }
        __builtin_amdgcn_s_setprio(0);

        // ---- epilogue: student-t + 128-col partial row sums ----
        float xsq = (p[0] + p[1]) + (p[2] + p[3]);
        xsq += __shfl_xor(xsq, 16);
        xsq += __shfl_xor(xsq, 32);
        // lane l now holds xsq of row trow + rg*16 + (l&15)

        float psum[4];
        #pragma unroll
        for (int r = 0; r < 4; ++r) {
            float xrr = __shfl(xsq, kch * 4 + r);
            float s = 0.f;
            #pragma unroll
            for (int f = 0; f < 8; ++f) {
                float d2 = xrr - 2.0f * acc[f][r] + cs[f];
                float qv = __builtin_amdgcn_rcpf(1.0f + d2);  // ALPHA=1 -> exp==1
                acc[f][r] = qv;
                s += qv;
            }
            s += __shfl_xor(s, 1);
            s += __shfl_xor(s, 2);
            s += __shfl_xor(s, 4);
            s += __shfl_xor(s, 8);
            psum[r] = s;   // sum over this wave's 128 cols, row kch*4+r
        }

        // ---- pairwise handshake (no block barrier, no vmcnt drain) ----
        if (c15 == 0) {
            #pragma unroll
            for (int r = 0; r < 4; ++r)
                ls_sum[t][ch][rg][kch * 4 + r] = psum[r];
        }
        asm volatile("s_waitcnt lgkmcnt(0)" ::: "memory");  // sums visible
        if (lane == 0)
            __atomic_store_n(&ls_flag[ch][rg], t + 1, __ATOMIC_RELAXED);

        volatile int* pf = (volatile int*)&ls_flag[ch ^ 1][rg];
        while (*pf <= t) { __builtin_amdgcn_s_sleep(1); }
        asm volatile("" ::: "memory");   // no hoisting of sum reads above spin

        const int row0t = trow + rg * 16;
        #pragma unroll
        for (int r = 0; r < 4; ++r) {
            float other = ls_sum[t][ch ^ 1][rg][kch * 4 + r];
            float inv = __builtin_amdgcn_rcpf(psum[r] + other);
            const size_t orow = (size_t)(row0t + kch * 4 + r) * KCL;
            #pragma unroll
            for (int f = 0; f < 8; ++f) {
                __builtin_nontemporal_store(acc[f][r] * inv,
                                            &out[orow + ch * 128 + f * 16 + c15]);
            }
        }
    }
}

extern "C" void kernel_launch(void* const* d_in, const int* in_sizes, int n_in,
                              void* d_out, int out_size, void* d_ws, size_t ws_size,
                              hipStream_t stream) {
    const float* x        = (const float*)d_in[0];
    const float* clusters = (const float*)d_in[1];
    float* out = (float*)d_out;

    // ws layout: [0, 128KB) clusters as bf16 ; [128KB, +1KB) c_sq f32
    unsigned short* cb  = (unsigned short*)d_ws;
    float*          csq = (float*)((char*)d_ws + (size_t)KCL * DDIM * sizeof(unsigned short));

    prep_kernel<<<KCL, 64, 0, stream>>>(clusters, cb, csq);
    fused_kernel<<<GRID, 512, 0, stream>>>(x, cb, csq, out);
}